// Round 8
// baseline (214.474 us; speedup 1.0000x reference)
//
#include <hip/hip_runtime.h>
#include <math.h>

// ACT skip-RNN, H=O=4096, I=4095 (xin=[flag,x], len 4096).
// R13: path-split A/B — half the weight stream nt (bypass L2), half cached
// (L2-allocate). Theory: the two paths' caps (nt ~3.9 TB/s, cached ~2.5 TB/s)
// are in different places (beyond-L2 read service vs L2 victimization churn)
// and superpose; null result => shared bottleneck => roofline.
//   k_prep  : zero ws ctl words + stage aligned xin into out[H..2H)
//   k_step0 : 1024 blocks x 256; wave = full row; W_ih nt, W_hh cached.
//   k_rest  : unchanged — halt decision from partials; rare path persistent.
//   k_out   : 512 blocks x 256; wave = 2 rows; rowA nt, rowB cached.
// out scratch: [0..H)=hpartials, [H..2H)=xin (both dead before k_out writes).
// ws float layout: [0]=cnt [1]=gen [4]=halted [5]=sel [6]=ponder [8]=last_acc
//   [16..32)=hdot[16] [32..32+H)=sb0 [32+H..32+2H)=sb1   (~33 KB)

#define H      4096
#define NMAX   16
#define THRESH 0.99f         // 1.0 - EPS

typedef float nf4 __attribute__((ext_vector_type(4)));   // native vec for nt loads

__device__ __forceinline__ float wave_reduce(float a) {
    #pragma unroll
    for (int off = 32; off > 0; off >>= 1) a += __shfl_down(a, off);
    return a;
}

// ---------------- k_prep: control-word zero + aligned xin staging ----------------
__global__ __launch_bounds__(256) void k_prep(
    const float* __restrict__ x, float* __restrict__ ws, float* __restrict__ out)
{
    const int i = blockIdx.x * 256 + threadIdx.x;
    if (i < 32) ws[i] = 0.f;               // cnt/gen/halted/sel/ponder/hdot
    if (i == 0) out[H] = 0.f;              // xin[0] flag slot (t==0 flag via W col 0)
    if (i < H - 1) out[H + 1 + i] = x[i];
}

// ---------------- k_step0: step-0 matvec ----------------
// 1024 blocks x 256 thr; wave w owns row bid*4+w. W_ih stream = nt (no L2
// allocate); W_hh stream = cached (L2-allocate path). Ping-pong batches kept.
__global__ __launch_bounds__(256, 4) void k_step0(
    const float* __restrict__ s0,     const float* __restrict__ h0,
    const float* __restrict__ W_ih,   const float* __restrict__ b_ih,
    const float* __restrict__ W_hh,   const float* __restrict__ b_hh,
    const float* __restrict__ W_halt,
    float* __restrict__ ws, float* __restrict__ out)
{
    if (h0[0] >= THRESH) return;           // ACT loop never executes

    const int tid  = threadIdx.x, bid = blockIdx.x;
    const int wave = tid >> 6,   lane = tid & 63;
    const int row  = (bid << 2) + wave;    // 1024 x 4 = 4096 rows

    const nf4*    wi4 = (const nf4*)(W_ih + (size_t)row * H);      // nt stream
    const float4* wh4 = (const float4*)(W_hh + (size_t)row * H);   // cached stream
    const float4* xv4 = (const float4*)(out + H);   // staged xin (L2-hot)
    const float4* sv4 = (const float4*)s0;          // L2-hot

    nf4    A[8], B[8];       // nt ping-pong (W_ih)
    float4 C[8], D[8];       // cached ping-pong (W_hh)
    #pragma unroll
    for (int k = 0; k < 8; ++k)
        A[k] = __builtin_nontemporal_load(&wi4[lane + (k << 6)]);
    #pragma unroll
    for (int k = 0; k < 8; ++k) C[k] = wh4[lane + (k << 6)];
    #pragma unroll
    for (int k = 0; k < 8; ++k)
        B[k] = __builtin_nontemporal_load(&wi4[lane + ((k + 8) << 6)]);
    #pragma unroll
    for (int k = 0; k < 8; ++k) D[k] = wh4[lane + ((k + 8) << 6)];

    float a0 = 0.f, a1 = 0.f;
    #pragma unroll
    for (int k = 0; k < 8; ++k) {
        float4 v = xv4[lane + (k << 6)];
        a0 += A[k].x*v.x + A[k].y*v.y + A[k].z*v.z + A[k].w*v.w;
    }
    #pragma unroll
    for (int k = 0; k < 8; ++k) {
        float4 v = sv4[lane + (k << 6)];
        a1 += C[k].x*v.x + C[k].y*v.y + C[k].z*v.z + C[k].w*v.w;
    }
    #pragma unroll
    for (int k = 0; k < 8; ++k) {
        float4 v = xv4[lane + ((k + 8) << 6)];
        a0 += B[k].x*v.x + B[k].y*v.y + B[k].z*v.z + B[k].w*v.w;
    }
    #pragma unroll
    for (int k = 0; k < 8; ++k) {
        float4 v = sv4[lane + ((k + 8) << 6)];
        a1 += D[k].x*v.x + D[k].y*v.y + D[k].z*v.z + D[k].w*v.w;
    }

    float a = wave_reduce(a0 + a1);
    if (lane == 0) {
        float z = a + b_ih[row] + b_hh[row] + W_ih[(size_t)row * H];  // xin[0]=1
        float s1 = tanhf(z);
        ws[32 + row] = s1;                 // sb0 = s1
        out[row] = W_halt[row] * s1;       // private halt partial
    }
}

// ---------------- k_rest: halt decision + rare path (steps 1..15) ----------------
#define RG   256
#define RT   256

__device__ __forceinline__ void grid_barrier(int* cnt, int* gen) {
    __syncthreads();
    if (threadIdx.x == 0) {
        __threadfence();
        int g = __hip_atomic_load(gen, __ATOMIC_RELAXED, __HIP_MEMORY_SCOPE_AGENT);
        int prev = __hip_atomic_fetch_add(cnt, 1, __ATOMIC_ACQ_REL, __HIP_MEMORY_SCOPE_AGENT);
        if (prev == RG - 1) {
            __hip_atomic_store(cnt, 0, __ATOMIC_RELAXED, __HIP_MEMORY_SCOPE_AGENT);
            __hip_atomic_fetch_add(gen, 1, __ATOMIC_RELEASE, __HIP_MEMORY_SCOPE_AGENT);
        } else {
            while (__hip_atomic_load(gen, __ATOMIC_ACQUIRE, __HIP_MEMORY_SCOPE_AGENT) == g)
                __builtin_amdgcn_s_sleep(8);
        }
        __threadfence();
    }
    __syncthreads();
}

__global__ __launch_bounds__(RT) void k_rest(
    const float* __restrict__ x,
    const float* __restrict__ h0,
    const float* __restrict__ W_ih,   const float* __restrict__ b_ih,
    const float* __restrict__ W_hh,   const float* __restrict__ b_hh,
    const float* __restrict__ W_halt, const float* __restrict__ b_halt,
    const float* __restrict__ hpart,  float* ws)
{
    int* wsI = (int*)ws;
    if (h0[0] >= THRESH) return;     // no steps ran at all

    const int tid = threadIdx.x, bid = blockIdx.x;
    const int wave = tid >> 6, lane = tid & 63;

    // ---- recompute step-0 halt decision from partials (uniform across blocks)
    {
        const float4* p4 = (const float4*)hpart;   // out[0..H) as H/4 float4
        float a = 0.f;
        #pragma unroll
        for (int j = 0; j < 4; ++j) {
            float4 v = p4[tid + (j << 8)];
            a += v.x + v.y + v.z + v.w;
        }
        a = wave_reduce(a);
        __shared__ float pr[4];
        if (lane == 0) pr[wave] = a;
        __syncthreads();
        float hd  = pr[0] + pr[1] + pr[2] + pr[3];
        float sg  = 1.f / (1.f + expf(-(hd + b_halt[0])));
        float acc0 = h0[0] + 2.f * sg;
        if (acc0 >= THRESH) {        // halted at step 0: common case
            if (bid == 0 && tid == 0) {
                wsI[4] = 1; wsI[5] = 0; wsI[6] = 0; ws[8] = acc0;
            }
            return;
        }
        if (bid == 0 && tid == 0) { wsI[4] = 0; }
        __syncthreads();
    }

    float* hdot = ws + 16;
    float* sb0  = ws + 32;
    float* sb1  = ws + 32 + H;

    __shared__ float xl[H];
    __shared__ float sl[H];
    if (tid == 0) xl[0] = 0.f;       // flag = 0 for all t >= 1
    for (int i = tid; i < H - 1; i += RT) xl[i + 1] = x[i];

    // recompute acc0 locally (cheap, uniform)
    float acc;
    {
        const float4* p4 = (const float4*)hpart;
        float a = 0.f;
        #pragma unroll
        for (int j = 0; j < 4; ++j) {
            float4 v = p4[tid + (j << 8)];
            a += v.x + v.y + v.z + v.w;
        }
        a = wave_reduce(a);
        __shared__ float pr2[4];
        if (lane == 0) pr2[wave] = a;
        __syncthreads();
        float hd = pr2[0] + pr2[1] + pr2[2] + pr2[3];
        acc = h0[0] + 2.f / (1.f + expf(-(hd + b_halt[0])));
    }
    int   ponder = 1;
    const float bh = b_halt[0];
    bool  halted = false;
    int   sel = 0;
    float last_acc = 0.f;

    for (int t = 1; t < NMAX; ++t) {
        const float* scur = (t & 1) ? sb0 : sb1;
        float*       snew = (t & 1) ? sb1 : sb0;

        __syncthreads();
        for (int i = tid; i < H / 4; i += RT)
            ((float4*)sl)[i] = ((const float4*)scur)[i];
        __syncthreads();

        for (int r = 0; r < 4; ++r) {
            const int row = bid * 16 + r * 4 + wave;
            const float4* wih = (const float4*)(W_ih + (size_t)row * H);
            const float4* whh = (const float4*)(W_hh + (size_t)row * H);
            float a0 = 0.f, a1 = 0.f;
            #pragma unroll 4
            for (int k = 0; k < 16; ++k) {
                const int idx = lane + (k << 6);
                float4 wa = wih[idx], wb = whh[idx];
                float4 va = ((const float4*)xl)[idx], vb = ((const float4*)sl)[idx];
                a0 += wa.x*va.x + wa.y*va.y + wa.z*va.z + wa.w*va.w;
                a1 += wb.x*vb.x + wb.y*vb.y + wb.z*vb.z + wb.w*vb.w;
            }
            float a = wave_reduce(a0 + a1);
            if (lane == 0) {
                float sv = tanhf(a + b_ih[row] + b_hh[row]);
                snew[row] = sv;
                atomicAdd(&hdot[t], W_halt[row] * sv);   // rare path: contention OK
            }
        }

        grid_barrier((int*)ws, (int*)ws + 1);

        float hd = ((volatile float*)hdot)[t];
        float sg = 1.f / (1.f + expf(-(hd + bh)));
        acc += 2.f * sg;
        if (acc >= THRESH) { halted = true; last_acc = acc; sel = (t & 1) ? 1 : 0; break; }
        ponder++;
    }

    if (bid == 0 && tid == 0) {
        wsI[4] = halted ? 1 : 0;
        wsI[5] = sel;
        wsI[6] = ponder;
        ws[8]  = last_acc;
    }
}

// ---------------- k_out: output matvec + epilogue ----------------
// 512 blocks x 256 thr; wave = 2 rows (rowA nt, rowB cached).
__global__ __launch_bounds__(256, 4) void k_out(
    const float* __restrict__ s0,    const float* __restrict__ y0,
    const float* __restrict__ h0,
    const float* __restrict__ W_out, const float* __restrict__ b_out,
    const float* __restrict__ ws, float* __restrict__ out)
{
    const float h0v = h0[0];
    const int tid = threadIdx.x, bid = blockIdx.x;

    if (h0v >= THRESH) {             // binarize(h0)==1: pass-through
        const int i = bid * 256 + tid;
        if (i < H) { out[i] = y0[i]; out[H + i] = s0[i]; }
        if (i == 0) { out[2*H] = 0.f; out[2*H + 1] = h0v - 1.f; }
        return;
    }

    const int* wsI = (const int*)ws;
    if (!wsI[4]) {                   // never halted within NMAX steps
        const int i = bid * 256 + tid;
        if (i < H) { out[i] = 0.f; out[H + i] = 0.f; }
        if (i == 0) { out[2*H] = (float)wsI[6]; out[2*H + 1] = -1.f; }
        return;
    }

    const float* sfin = ws + 32 + (wsI[5] ? H : 0);
    const int wave = tid >> 6, lane = tid & 63;
    const int rowA = (bid << 2) + wave;        // 512 x 4 = 2048
    const int rowB = rowA + 2048;

    const nf4*    wA4 = (const nf4*)(W_out + (size_t)rowA * H);     // nt
    const float4* wB4 = (const float4*)(W_out + (size_t)rowB * H);  // cached
    const float4* v4  = (const float4*)sfin;

    nf4    A[8], B[8];
    float4 C[8], D[8];
    #pragma unroll
    for (int k = 0; k < 8; ++k)
        A[k] = __builtin_nontemporal_load(&wA4[lane + (k << 6)]);
    #pragma unroll
    for (int k = 0; k < 8; ++k) C[k] = wB4[lane + (k << 6)];
    #pragma unroll
    for (int k = 0; k < 8; ++k)
        B[k] = __builtin_nontemporal_load(&wA4[lane + ((k + 8) << 6)]);
    #pragma unroll
    for (int k = 0; k < 8; ++k) D[k] = wB4[lane + ((k + 8) << 6)];

    float accA = 0.f, accB = 0.f;
    #pragma unroll
    for (int k = 0; k < 8; ++k) {
        float4 v = v4[lane + (k << 6)];
        accA += A[k].x*v.x + A[k].y*v.y + A[k].z*v.z + A[k].w*v.w;
        accB += C[k].x*v.x + C[k].y*v.y + C[k].z*v.z + C[k].w*v.w;
    }
    #pragma unroll
    for (int k = 0; k < 8; ++k) {
        float4 v = v4[lane + ((k + 8) << 6)];
        accA += B[k].x*v.x + B[k].y*v.y + B[k].z*v.z + B[k].w*v.w;
        accB += D[k].x*v.x + D[k].y*v.y + D[k].z*v.z + D[k].w*v.w;
    }

    float ra = wave_reduce(accA);
    float rb = wave_reduce(accB);
    if (lane == 0) {
        out[rowA]     = ra + b_out[rowA];
        out[rowB]     = rb + b_out[rowB];
        out[H + rowA] = sfin[rowA];
        out[H + rowB] = sfin[rowB];
        if (bid == 0 && wave == 0) {
            out[2*H]     = (float)wsI[6];
            out[2*H + 1] = ws[8] - 1.f;
        }
    }
}

extern "C" void kernel_launch(void* const* d_in, const int* in_sizes, int n_in,
                              void* d_out, int out_size, void* d_ws, size_t ws_size,
                              hipStream_t stream) {
    const float* x      = (const float*)d_in[0];
    const float* s0     = (const float*)d_in[1];
    const float* y0     = (const float*)d_in[2];
    const float* h0     = (const float*)d_in[3];
    const float* W_ih   = (const float*)d_in[4];
    const float* b_ih   = (const float*)d_in[5];
    const float* W_hh   = (const float*)d_in[6];
    const float* b_hh   = (const float*)d_in[7];
    const float* W_halt = (const float*)d_in[8];
    const float* b_halt = (const float*)d_in[9];
    const float* W_out  = (const float*)d_in[10];
    const float* b_out  = (const float*)d_in[11];
    float* out = (float*)d_out;
    float* ws  = (float*)d_ws;   // (32 + 2*4096)*4 B ≈ 33 KB used

    k_prep<<<dim3(16),   dim3(256), 0, stream>>>(x, ws, out);
    k_step0<<<dim3(1024), dim3(256), 0, stream>>>(
        s0, h0, W_ih, b_ih, W_hh, b_hh, W_halt, ws, out);
    k_rest<<<dim3(RG),   dim3(RT),  0, stream>>>(
        x, h0, W_ih, b_ih, W_hh, b_hh, W_halt, b_halt, out, ws);
    k_out<<<dim3(512),   dim3(256), 0, stream>>>(
        s0, y0, h0, W_out, b_out, ws, out);
}